// Round 1
// baseline (57472.736 us; speedup 1.0000x reference)
//
#include <hip/hip_runtime.h>

#define T_STEPS 32768
#define HID 1024
#define NWG 64      // workgroups in recurrent kernel
#define RPG 16      // rows per workgroup = HID/NWG

// ---------------- bf16 helpers (manual, RNE) ----------------
__device__ __forceinline__ unsigned short f2bf(float f) {
    unsigned u = __float_as_uint(f);
    u = (u + 0x7fffu + ((u >> 16) & 1u)) >> 16;
    return (unsigned short)u;
}
__device__ __forceinline__ float bf2f(unsigned short s) {
    return __uint_as_float(((unsigned)s) << 16);
}

// ---------------- Kernel 1: pre[t][j] = x[t,:] . W_x[j,:] + b_i2h[j] ----------------
// x: (T,1024) fp32 row-major. W_i2h: (1024,2048) row-major, W_x = cols [0,1024).
// pre stored as bf16 ushort (T,1024).
#define BM 64
#define BN 64
#define BK 16
#define LDST 68   // padded LDS row stride (keeps 16B alignment, spreads banks)

__global__ void __launch_bounds__(256) pre_gemm(
    const float* __restrict__ x, const float* __restrict__ Wi,
    const float* __restrict__ b, unsigned short* __restrict__ pre)
{
    __shared__ float As[BK * LDST];
    __shared__ float Bs[BK * LDST];
    const int tid = threadIdx.x;
    const int t0 = blockIdx.x * BM;
    const int j0 = blockIdx.y * BN;
    const int row = tid >> 2;   // 0..63
    const int kq  = tid & 3;    // 0..3
    const int tx  = tid & 15;   // 0..15
    const int ty  = tid >> 4;   // 0..15

    float c[4][4];
#pragma unroll
    for (int i = 0; i < 4; ++i)
#pragma unroll
        for (int j = 0; j < 4; ++j) c[i][j] = 0.f;

    for (int k0 = 0; k0 < 1024; k0 += BK) {
        float4 a4 = *(const float4*)&x[(size_t)(t0 + row) * 1024 + k0 + 4 * kq];
        float4 b4 = *(const float4*)&Wi[(size_t)(j0 + row) * 2048 + k0 + 4 * kq];
        __syncthreads();
        As[(4 * kq + 0) * LDST + row] = a4.x;
        As[(4 * kq + 1) * LDST + row] = a4.y;
        As[(4 * kq + 2) * LDST + row] = a4.z;
        As[(4 * kq + 3) * LDST + row] = a4.w;
        Bs[(4 * kq + 0) * LDST + row] = b4.x;
        Bs[(4 * kq + 1) * LDST + row] = b4.y;
        Bs[(4 * kq + 2) * LDST + row] = b4.z;
        Bs[(4 * kq + 3) * LDST + row] = b4.w;
        __syncthreads();
#pragma unroll
        for (int kk = 0; kk < BK; ++kk) {
            float4 av = *(const float4*)&As[kk * LDST + 4 * ty];
            float4 bv = *(const float4*)&Bs[kk * LDST + 4 * tx];
            c[0][0] = fmaf(av.x, bv.x, c[0][0]); c[0][1] = fmaf(av.x, bv.y, c[0][1]);
            c[0][2] = fmaf(av.x, bv.z, c[0][2]); c[0][3] = fmaf(av.x, bv.w, c[0][3]);
            c[1][0] = fmaf(av.y, bv.x, c[1][0]); c[1][1] = fmaf(av.y, bv.y, c[1][1]);
            c[1][2] = fmaf(av.y, bv.z, c[1][2]); c[1][3] = fmaf(av.y, bv.w, c[1][3]);
            c[2][0] = fmaf(av.z, bv.x, c[2][0]); c[2][1] = fmaf(av.z, bv.y, c[2][1]);
            c[2][2] = fmaf(av.z, bv.z, c[2][2]); c[2][3] = fmaf(av.z, bv.w, c[2][3]);
            c[3][0] = fmaf(av.w, bv.x, c[3][0]); c[3][1] = fmaf(av.w, bv.y, c[3][1]);
            c[3][2] = fmaf(av.w, bv.z, c[3][2]); c[3][3] = fmaf(av.w, bv.w, c[3][3]);
        }
    }

    float4 bias = *(const float4*)&b[j0 + 4 * tx];
#pragma unroll
    for (int i = 0; i < 4; ++i) {
        int r = t0 + 4 * ty + i;
        ushort4 u;
        u.x = f2bf(c[i][0] + bias.x);
        u.y = f2bf(c[i][1] + bias.y);
        u.z = f2bf(c[i][2] + bias.z);
        u.w = f2bf(c[i][3] + bias.w);
        *(ushort4*)&pre[(size_t)r * 1024 + j0 + 4 * tx] = u;
    }
}

// ---------------- Kernel 2: serial recurrence, persistent data-flow ----------------
// hp[2][1024] of packed (tag<<32 | float_bits). Step t reads tags==t-1 from
// hp[(t-1)&1], writes tags==t into hp[t&1]. Two-deep parity buffer: writer of
// step t has observed all of t-1, which implies all readers of t-2 are done,
// so overwriting the t-2 slot is safe.

__device__ __forceinline__ unsigned long long pack_hv(float v, unsigned t) {
    return ((unsigned long long)t << 32) | (unsigned long long)__float_as_uint(v);
}

__device__ __forceinline__ void poll_stage(unsigned long long* src, float* dst,
                                           unsigned tg, int e0)
{
    unsigned long long p0, p1, p2, p3;
    for (;;) {
        p0 = __hip_atomic_load(&src[e0 + 0], __ATOMIC_RELAXED, __HIP_MEMORY_SCOPE_AGENT);
        p1 = __hip_atomic_load(&src[e0 + 1], __ATOMIC_RELAXED, __HIP_MEMORY_SCOPE_AGENT);
        p2 = __hip_atomic_load(&src[e0 + 2], __ATOMIC_RELAXED, __HIP_MEMORY_SCOPE_AGENT);
        p3 = __hip_atomic_load(&src[e0 + 3], __ATOMIC_RELAXED, __HIP_MEMORY_SCOPE_AGENT);
        if ((unsigned)(p0 >> 32) == tg && (unsigned)(p1 >> 32) == tg &&
            (unsigned)(p2 >> 32) == tg && (unsigned)(p3 >> 32) == tg) break;
    }
    dst[e0 + 0] = __uint_as_float((unsigned)p0);
    dst[e0 + 1] = __uint_as_float((unsigned)p1);
    dst[e0 + 2] = __uint_as_float((unsigned)p2);
    dst[e0 + 3] = __uint_as_float((unsigned)p3);
}

__device__ __forceinline__ float wave_sum(float v) {
#pragma unroll
    for (int off = 32; off > 0; off >>= 1) v += __shfl_xor(v, off, 64);
    return v;
}

__global__ void __launch_bounds__(256) rnn_rec(
    const unsigned short* __restrict__ pre,
    const float* __restrict__ Wi,    // W_h = Wi[:, 1024:2048]
    const float* __restrict__ Wo,    // (1024,1024)
    const float* __restrict__ bo,
    float* __restrict__ out,
    unsigned long long* hp)          // hp[2][1024] in d_ws
{
    const int g   = blockIdx.x;
    const int tid = threadIdx.x;
    const int w   = tid >> 6;    // wave 0..3
    const int l   = tid & 63;    // lane
    const int rowbase = g * RPG + w * 4;   // this wave's 4 rows
    const int e0 = tid * 4;                // this thread's 4 h-elements

    __shared__ float hl[2][HID];

    // W_h fragment resident in VGPRs: 4 rows x 16 k (k = 4l + 256j + 0..3)
    float4 wv[4][4];
#pragma unroll
    for (int rr = 0; rr < 4; ++rr)
#pragma unroll
        for (int j = 0; j < 4; ++j)
            wv[rr][j] = *(const float4*)&Wi[(size_t)(rowbase + rr) * 2048 + 1024 + 4 * l + 256 * j];

    // init h_0 = 0 with tag 0 into parity buffer 0 (own slice only)
    if (tid < RPG)
        __hip_atomic_store(&hp[g * RPG + tid], pack_hv(0.f, 0u),
                           __ATOMIC_RELAXED, __HIP_MEMORY_SCOPE_AGENT);

    for (int t = 1; t <= T_STEPS; ++t) {
        // issue pre-activation load early (hidden behind the poll)
        float prev = 0.f;
        if (l < 4) prev = bf2f(pre[(size_t)(t - 1) * HID + rowbase + l]);

        unsigned long long* src = &hp[((t - 1) & 1) * HID];
        float* dst = hl[(t - 1) & 1];
        poll_stage(src, dst, (unsigned)(t - 1), e0);
        __syncthreads();

        float s0 = 0.f, s1 = 0.f, s2 = 0.f, s3 = 0.f;
#pragma unroll
        for (int j = 0; j < 4; ++j) {
            float4 hv = *(const float4*)&dst[4 * l + 256 * j];
            s0 = fmaf(wv[0][j].x, hv.x, s0); s0 = fmaf(wv[0][j].y, hv.y, s0);
            s0 = fmaf(wv[0][j].z, hv.z, s0); s0 = fmaf(wv[0][j].w, hv.w, s0);
            s1 = fmaf(wv[1][j].x, hv.x, s1); s1 = fmaf(wv[1][j].y, hv.y, s1);
            s1 = fmaf(wv[1][j].z, hv.z, s1); s1 = fmaf(wv[1][j].w, hv.w, s1);
            s2 = fmaf(wv[2][j].x, hv.x, s2); s2 = fmaf(wv[2][j].y, hv.y, s2);
            s2 = fmaf(wv[2][j].z, hv.z, s2); s2 = fmaf(wv[2][j].w, hv.w, s2);
            s3 = fmaf(wv[3][j].x, hv.x, s3); s3 = fmaf(wv[3][j].y, hv.y, s3);
            s3 = fmaf(wv[3][j].z, hv.z, s3); s3 = fmaf(wv[3][j].w, hv.w, s3);
        }
        s0 = wave_sum(s0); s1 = wave_sum(s1); s2 = wave_sum(s2); s3 = wave_sum(s3);

        if (l < 4) {
            float sv = (l == 0) ? s0 : (l == 1) ? s1 : (l == 2) ? s2 : s3;
            float h = tanhf(prev + sv);
            __hip_atomic_store(&hp[(t & 1) * HID + rowbase + l], pack_hv(h, (unsigned)t),
                               __ATOMIC_RELAXED, __HIP_MEMORY_SCOPE_AGENT);
        }
        // no trailing barrier needed: next step stages into the other LDS
        // parity buffer, and its own poll can't pass until this WG's waves
        // have all produced (their rows are part of the 1024 tags checked).
    }

    // ---- final projection: out = h_T . W_h2o^T + b_h2o ----
    {
        unsigned long long* src = &hp[(T_STEPS & 1) * HID];
        float* dst = hl[0];
        poll_stage(src, dst, (unsigned)T_STEPS, e0);
        __syncthreads();

        float s0 = 0.f, s1 = 0.f, s2 = 0.f, s3 = 0.f;
#pragma unroll
        for (int j = 0; j < 4; ++j) {
            float4 hv = *(const float4*)&dst[4 * l + 256 * j];
            float4 w0 = *(const float4*)&Wo[(size_t)(rowbase + 0) * 1024 + 4 * l + 256 * j];
            float4 w1 = *(const float4*)&Wo[(size_t)(rowbase + 1) * 1024 + 4 * l + 256 * j];
            float4 w2 = *(const float4*)&Wo[(size_t)(rowbase + 2) * 1024 + 4 * l + 256 * j];
            float4 w3 = *(const float4*)&Wo[(size_t)(rowbase + 3) * 1024 + 4 * l + 256 * j];
            s0 = fmaf(w0.x, hv.x, s0); s0 = fmaf(w0.y, hv.y, s0);
            s0 = fmaf(w0.z, hv.z, s0); s0 = fmaf(w0.w, hv.w, s0);
            s1 = fmaf(w1.x, hv.x, s1); s1 = fmaf(w1.y, hv.y, s1);
            s1 = fmaf(w1.z, hv.z, s1); s1 = fmaf(w1.w, hv.w, s1);
            s2 = fmaf(w2.x, hv.x, s2); s2 = fmaf(w2.y, hv.y, s2);
            s2 = fmaf(w2.z, hv.z, s2); s2 = fmaf(w2.w, hv.w, s2);
            s3 = fmaf(w3.x, hv.x, s3); s3 = fmaf(w3.y, hv.y, s3);
            s3 = fmaf(w3.z, hv.z, s3); s3 = fmaf(w3.w, hv.w, s3);
        }
        s0 = wave_sum(s0); s1 = wave_sum(s1); s2 = wave_sum(s2); s3 = wave_sum(s3);
        if (l < 4) {
            float sv = (l == 0) ? s0 : (l == 1) ? s1 : (l == 2) ? s2 : s3;
            out[rowbase + l] = sv + bo[rowbase + l];
        }
    }
}

extern "C" void kernel_launch(void* const* d_in, const int* in_sizes, int n_in,
                              void* d_out, int out_size, void* d_ws, size_t ws_size,
                              hipStream_t stream) {
    const float* x     = (const float*)d_in[0];   // (1, 32768, 1024)
    const float* W_i2h = (const float*)d_in[1];   // (1024, 2048)
    const float* b_i2h = (const float*)d_in[2];   // (1024,)
    const float* W_h2o = (const float*)d_in[3];   // (1024, 1024)
    const float* b_h2o = (const float*)d_in[4];   // (1024,)
    float* out = (float*)d_out;

    unsigned short* pre = (unsigned short*)d_ws;                       // 64 MB bf16
    unsigned long long* hp =
        (unsigned long long*)((char*)d_ws + (size_t)T_STEPS * HID * sizeof(unsigned short));

    pre_gemm<<<dim3(T_STEPS / BM, HID / BN), 256, 0, stream>>>(x, W_i2h, b_i2h, pre);
    rnn_rec<<<NWG, 256, 0, stream>>>(pre, W_i2h, W_h2o, b_h2o, out, hp);
}